// Round 2
// baseline (3442.389 us; speedup 1.0000x reference)
//
#include <hip/hip_runtime.h>
#include <hip/hip_bf16.h>

typedef __bf16 bf16_t;
typedef short short8 __attribute__((ext_vector_type(8)));
typedef float f32x4 __attribute__((ext_vector_type(4)));

__device__ inline short f2bs(float v) {
    bf16_t h = (bf16_t)v;
    return __builtin_bit_cast(short, h);
}

// ---------------- counts ----------------
__global__ __launch_bounds__(256) void count_kernel(const int* __restrict__ dst,
                                                    float* __restrict__ cnt, int E) {
    int e = blockIdx.x * 256 + threadIdx.x;
    if (e < E) atomicAdd(&cnt[dst[e]], 1.0f);
}

__global__ __launch_bounds__(256) void invert_kernel(float* __restrict__ c, int n) {
    int i = blockIdx.x * 256 + threadIdx.x;
    if (i < n) c[i] = 1.0f / fmaxf(c[i], 1.0f);
}

// ---------------- scatter-add (atomic, f32 features) ----------------
// 32 threads per edge, 2 features per thread.
__global__ __launch_bounds__(256) void scatter_kernel(const float* __restrict__ x,
                                                      const int* __restrict__ src,
                                                      const int* __restrict__ dst,
                                                      float* __restrict__ acc, int E) {
    int gid = blockIdx.x * 256 + threadIdx.x;
    int e = gid >> 5;
    if (e >= E) return;
    int l2 = gid & 31;
    int s = src[e], d = dst[e];
    const float2 v = *reinterpret_cast<const float2*>(x + (size_t)s * 64 + l2 * 2);
    float* ap = acc + (size_t)d * 64 + l2 * 2;
    atomicAdd(ap,     v.x);
    atomicAdd(ap + 1, v.y);
}

// ---------------- fused linear (MFMA bf16 internals, f32 I/O) ----------------
// out[N,64] = sum over streams + bias, optional relu.
// Streams: NM mean-streams (f32 accum * inv_cnt), x-stream applied with NX weight mats.
// Wave computes 16 rows x 64 cols: 2 k-steps x 4 col-tiles of mfma_f32_16x16x32_bf16.
// Layouts (m89/m120-verified): A[m=lane&15][k=(lane>>4)*8+j],
// B[k=(lane>>4)*8+j][n=lane&15], C/D row=(lane>>4)*4+reg, col=lane&15.
template <int NM, int NX, int RELU>
__global__ __launch_bounds__(256) void lin_kernel(
    const float* __restrict__ m0acc, const float* __restrict__ m0inv,
    const float* __restrict__ m1acc, const float* __restrict__ m1inv,
    const float* __restrict__ x,
    const float* __restrict__ Wm0, const float* __restrict__ Wm1,
    const float* __restrict__ Wx0, const float* __restrict__ Wx1,
    const float* __restrict__ bias0, const float* __restrict__ bias1,
    float* __restrict__ out, int nrows) {
    const int lane = threadIdx.x & 63;
    const int wave = threadIdx.x >> 6;
    const int row0 = blockIdx.x * 64 + wave * 16;
    if (row0 >= nrows) return;
    const int r = lane & 15;
    const int q = lane >> 4;

    // Load weight fragments (held in registers for the whole kernel), f32 -> bf16.
    short8 wm0f[2][4], wm1f[2][4], wx0f[2][4], wx1f[2][4];
#pragma unroll
    for (int ks = 0; ks < 2; ks++) {
#pragma unroll
        for (int t = 0; t < 4; t++) {
            int col = t * 16 + r;
            int k0 = ks * 32 + q * 8;
#pragma unroll
            for (int j = 0; j < 8; j++) {
                int widx = (k0 + j) * 64 + col;
                if (NM >= 1) wm0f[ks][t][j] = f2bs(Wm0[widx]);
                if (NM >= 2) wm1f[ks][t][j] = f2bs(Wm1[widx]);
                if (NX >= 1) wx0f[ks][t][j] = f2bs(Wx0[widx]);
                if (NX >= 2) wx1f[ks][t][j] = f2bs(Wx1[widx]);
            }
        }
    }

    // Bias into accumulators (C col = t*16+r, same for all 4 regs).
    f32x4 acc[4];
#pragma unroll
    for (int t = 0; t < 4; t++) {
        float bv = bias0[t * 16 + r];
        if (bias1) bv += bias1[t * 16 + r];
        acc[t][0] = bv; acc[t][1] = bv; acc[t][2] = bv; acc[t][3] = bv;
    }

    const int arow = row0 + r;       // A-fragment row for this lane
    const bool avalid = arow < nrows;

    // mean streams
    if (NM >= 1) {
        float inv0 = avalid ? m0inv[arow] : 0.0f;
#pragma unroll
        for (int ks = 0; ks < 2; ks++) {
            short8 af;
            if (avalid) {
                const float* p = m0acc + (size_t)arow * 64 + q * 8 + ks * 32;
#pragma unroll
                for (int j = 0; j < 8; j++) af[j] = f2bs(p[j] * inv0);
            } else {
#pragma unroll
                for (int j = 0; j < 8; j++) af[j] = 0;
            }
#pragma unroll
            for (int t = 0; t < 4; t++)
                acc[t] = __builtin_amdgcn_mfma_f32_16x16x32_bf16(af, wm0f[ks][t], acc[t], 0, 0, 0);
        }
    }
    if (NM >= 2) {
        float inv1 = avalid ? m1inv[arow] : 0.0f;
#pragma unroll
        for (int ks = 0; ks < 2; ks++) {
            short8 af;
            if (avalid) {
                const float* p = m1acc + (size_t)arow * 64 + q * 8 + ks * 32;
#pragma unroll
                for (int j = 0; j < 8; j++) af[j] = f2bs(p[j] * inv1);
            } else {
#pragma unroll
                for (int j = 0; j < 8; j++) af[j] = 0;
            }
#pragma unroll
            for (int t = 0; t < 4; t++)
                acc[t] = __builtin_amdgcn_mfma_f32_16x16x32_bf16(af, wm1f[ks][t], acc[t], 0, 0, 0);
        }
    }

    // x stream (A-frags reused across NX weight sets)
    if (NX >= 1) {
#pragma unroll
        for (int ks = 0; ks < 2; ks++) {
            short8 xf;
            if (avalid) {
                const float* p = x + (size_t)arow * 64 + q * 8 + ks * 32;
#pragma unroll
                for (int j = 0; j < 8; j++) xf[j] = f2bs(p[j]);
            } else {
#pragma unroll
                for (int j = 0; j < 8; j++) xf[j] = 0;
            }
#pragma unroll
            for (int t = 0; t < 4; t++)
                acc[t] = __builtin_amdgcn_mfma_f32_16x16x32_bf16(xf, wx0f[ks][t], acc[t], 0, 0, 0);
            if (NX >= 2) {
#pragma unroll
                for (int t = 0; t < 4; t++)
                    acc[t] = __builtin_amdgcn_mfma_f32_16x16x32_bf16(xf, wx1f[ks][t], acc[t], 0, 0, 0);
            }
        }
    }

    // Epilogue: C/D row = row0 + q*4 + reg, col = t*16 + r.  f32 stores.
#pragma unroll
    for (int t = 0; t < 4; t++) {
#pragma unroll
        for (int rr = 0; rr < 4; rr++) {
            int row = row0 + q * 4 + rr;
            if (row < nrows) {
                float v = acc[t][rr];
                if (RELU) v = fmaxf(v, 0.0f);
                out[(size_t)row * 64 + t * 16 + r] = v;
            }
        }
    }
}

// ---------------- launch ----------------
extern "C" void kernel_launch(void* const* d_in, const int* in_sizes, int n_in,
                              void* d_out, int out_size, void* d_ws, size_t ws_size,
                              hipStream_t stream) {
    const float* xA_in = (const float*)d_in[0];
    const float* xB_in = (const float*)d_in[1];
    const float* Wn = (const float*)d_in[2];
    const float* Wr = (const float*)d_in[3];
    const float* b = (const float*)d_in[4];
    const float* W_out = (const float*)d_in[5];
    const float* b_out = (const float*)d_in[6];
    const int* src0 = (const int*)d_in[7];
    const int* dst0 = (const int*)d_in[8];
    const int* src1 = (const int*)d_in[9];
    const int* dst1 = (const int*)d_in[10];
    const int* src2 = (const int*)d_in[11];
    const int* dst2 = (const int*)d_in[12];

    const int NA = in_sizes[0] / 64;
    const int NB = in_sizes[1] / 64;
    const int E = in_sizes[7];

    // workspace layout (f32 everywhere):
    // acc0 [NA*64] | acc1 [NA*64] | xA0 [NA*64] | xB0 [NB*64]
    // | cntB [NB] | cntA1 [NA] | cntA2 [NA]        (~130 MB for 100k/100k)
    float* acc0 = (float*)d_ws;
    float* acc1 = acc0 + (size_t)NA * 64;
    float* xA0 = acc1 + (size_t)NA * 64;
    float* xB0 = xA0 + (size_t)NA * 64;
    float* cntB = xB0 + (size_t)NB * 64;
    float* cntA1 = cntB + NB;
    float* cntA2 = cntA1 + NA;

    const int cntBlocks = (E + 255) / 256;
    const int scatBlocks = (E * 32 + 255) / 256;

    // counts: once (graph is static across both layers)
    hipMemsetAsync(cntB, 0, (size_t)(NB + NA + NA) * 4, stream);
    count_kernel<<<cntBlocks, 256, 0, stream>>>(dst0, cntB, E);
    count_kernel<<<cntBlocks, 256, 0, stream>>>(dst1, cntA1, E);
    count_kernel<<<cntBlocks, 256, 0, stream>>>(dst2, cntA2, E);
    invert_kernel<<<(NB + NA + NA + 255) / 256, 256, 0, stream>>>(cntB, NB + NA + NA);

    const float* xA = xA_in;
    const float* xB = xB_in;
    for (int l = 0; l < 2; l++) {
        float* xAn = (l == 0) ? xA0 : (float*)d_out;
        float* xBn = (l == 0) ? xB0 : ((float*)d_out + (size_t)NA * 64);

        // ---- B phase: new_B = mean(A->B) @ Wn[l,0] + x_B @ Wr[l,0] + b[l,0]
        hipMemsetAsync(acc0, 0, (size_t)NB * 64 * 4, stream);
        scatter_kernel<<<scatBlocks, 256, 0, stream>>>(xA, src0, dst0, acc0, E);
        lin_kernel<1, 1, 0><<<(NB + 63) / 64, 256, 0, stream>>>(
            acc0, cntB, nullptr, nullptr, xB,
            Wn + (size_t)(l * 3 + 0) * 4096, nullptr,
            Wr + (size_t)(l * 3 + 0) * 4096, nullptr,
            b + (size_t)(l * 3 + 0) * 64, nullptr, xBn, NB);

        // ---- A phase: new_A = mean(B->A)@Wn[l,1] + mean(A->A)@Wn[l,2]
        //               + x_A@Wr[l,1] + x_A@Wr[l,2] + b[l,1] + b[l,2]
        hipMemsetAsync(acc0, 0, (size_t)NA * 64 * 2 * 4, stream);  // acc0+acc1
        scatter_kernel<<<scatBlocks, 256, 0, stream>>>(xB, src1, dst1, acc0, E);
        scatter_kernel<<<scatBlocks, 256, 0, stream>>>(xA, src2, dst2, acc1, E);
        lin_kernel<2, 2, 0><<<(NA + 63) / 64, 256, 0, stream>>>(
            acc0, cntA1, acc1, cntA2, xA,
            Wn + (size_t)(l * 3 + 1) * 4096, Wn + (size_t)(l * 3 + 2) * 4096,
            Wr + (size_t)(l * 3 + 1) * 4096, Wr + (size_t)(l * 3 + 2) * 4096,
            b + (size_t)(l * 3 + 1) * 64, b + (size_t)(l * 3 + 2) * 64, xAn, NA);

        xA = xAn;
        xB = xBn;
    }

    // head: out = relu(x @ W_out + b_out), in place on d_out (row i reads only row i)
    lin_kernel<0, 1, 1><<<(NA + 63) / 64, 256, 0, stream>>>(
        nullptr, nullptr, nullptr, nullptr, xA,
        nullptr, nullptr, W_out, nullptr, b_out, nullptr, (float*)d_out, NA);
    lin_kernel<0, 1, 1><<<(NB + 63) / 64, 256, 0, stream>>>(
        nullptr, nullptr, nullptr, nullptr, xB,
        nullptr, nullptr, W_out, nullptr, b_out, nullptr,
        (float*)d_out + (size_t)NA * 64, NB);
}

// Round 3
// 1061.521 us; speedup vs baseline: 3.2429x; 3.2429x over previous
//
#include <hip/hip_runtime.h>
#include <hip/hip_bf16.h>

typedef __bf16 bf16_t;
typedef short short8 __attribute__((ext_vector_type(8)));
typedef float f32x4 __attribute__((ext_vector_type(4)));

__device__ inline short f2bs(float v) {
    bf16_t h = (bf16_t)v;
    return __builtin_bit_cast(short, h);
}

// ---------------- CSR build ----------------
__global__ __launch_bounds__(256) void count_kernel(const int* __restrict__ dst,
                                                    int* __restrict__ cnt, int goff, int E) {
    int e = blockIdx.x * 256 + threadIdx.x;
    if (e < E) atomicAdd(&cnt[goff + dst[e]], 1);
}

// scan step 1: per-block (1024 elems) sums
__global__ __launch_bounds__(256) void scan_reduce(const int* __restrict__ cnt, int n,
                                                   int* __restrict__ part) {
    __shared__ int sdata[256];
    int base = blockIdx.x * 1024;
    int s = 0;
    for (int j = threadIdx.x; j < 1024; j += 256) {
        int i = base + j;
        s += (i < n) ? cnt[i] : 0;
    }
    sdata[threadIdx.x] = s;
    __syncthreads();
    for (int off = 128; off > 0; off >>= 1) {
        if (threadIdx.x < off) sdata[threadIdx.x] += sdata[threadIdx.x + off];
        __syncthreads();
    }
    if (threadIdx.x == 0) part[blockIdx.x] = sdata[0];
}

// scan step 2: single block, exclusive scan of partials (G <= 1024)
__global__ __launch_bounds__(1024) void scan_part(int* __restrict__ part, int G) {
    __shared__ int sdata[1024];
    int tid = threadIdx.x;
    sdata[tid] = (tid < G) ? part[tid] : 0;
    __syncthreads();
    for (int off = 1; off < 1024; off <<= 1) {
        int t = (tid >= off) ? sdata[tid - off] : 0;
        __syncthreads();
        sdata[tid] += t;
        __syncthreads();
    }
    if (tid < G) part[tid] = (tid == 0) ? 0 : sdata[tid - 1];
}

// scan step 3: rescan each 1024-chunk, add block prefix, write exclusive offsets
__global__ __launch_bounds__(256) void scan_final(const int* __restrict__ cnt, int n,
                                                  const int* __restrict__ partscan,
                                                  int* __restrict__ off) {
    __shared__ int sdata[256];
    int base = blockIdx.x * 1024;
    int tid = threadIdx.x;
    int v[4];
    int s = 0;
#pragma unroll
    for (int j = 0; j < 4; j++) {
        int i = base + tid * 4 + j;
        v[j] = s;
        s += (i < n) ? cnt[i] : 0;
    }
    sdata[tid] = s;
    __syncthreads();
    for (int offd = 1; offd < 256; offd <<= 1) {
        int t = (tid >= offd) ? sdata[tid - offd] : 0;
        __syncthreads();
        sdata[tid] += t;
        __syncthreads();
    }
    int thread_excl = (tid == 0) ? 0 : sdata[tid - 1];
    int blockoff = partscan[blockIdx.x];
#pragma unroll
    for (int j = 0; j < 4; j++) {
        int i = base + tid * 4 + j;
        if (i < n) off[i] = blockoff + thread_excl + v[j];
    }
    if (blockIdx.x == gridDim.x - 1 && tid == 255) off[n] = blockoff + sdata[255];
}

__global__ __launch_bounds__(256) void fill_kernel(const int* __restrict__ src,
                                                   const int* __restrict__ dst,
                                                   const int* __restrict__ off,
                                                   int* __restrict__ cursor,
                                                   int* __restrict__ colidx,
                                                   int goff, int E) {
    int e = blockIdx.x * 256 + threadIdx.x;
    if (e >= E) return;
    int d = goff + dst[e];
    int pos = atomicAdd(&cursor[d], 1);
    colidx[off[d] + pos] = src[e];
}

// ---------------- gather-mean (no atomics) ----------------
// one wave per dst row; lane = feature; 2-edge unroll for ILP.
__global__ __launch_bounds__(256) void gather_mean(const float* __restrict__ x,
                                                   const int* __restrict__ colidx,
                                                   const int* __restrict__ off,
                                                   int goff, float* __restrict__ mean,
                                                   int nrows) {
    int wid = (blockIdx.x * 256 + threadIdx.x) >> 6;
    int lane = threadIdx.x & 63;
    if (wid >= nrows) return;
    int ci = goff + wid;
    int s0 = off[ci], s1 = off[ci + 1];
    float acc0 = 0.f, acc1 = 0.f;
    int e = s0;
    for (; e + 1 < s1; e += 2) {
        int sa = colidx[e], sb = colidx[e + 1];
        acc0 += x[(size_t)sa * 64 + lane];
        acc1 += x[(size_t)sb * 64 + lane];
    }
    if (e < s1) acc0 += x[(size_t)colidx[e] * 64 + lane];
    float deg = (float)(s1 - s0);
    mean[(size_t)wid * 64 + lane] = (acc0 + acc1) / fmaxf(deg, 1.0f);
}

// ---------------- fused linear (MFMA bf16 internals, f32 I/O) ----------------
// out[N,64] = [means]@Wm* + x@Wx* + bias, optional relu.
// Wave computes 16 rows x 64 cols: 2 k-steps x 4 col-tiles of mfma_f32_16x16x32_bf16.
// Layouts: A[m=lane&15][k=(lane>>4)*8+j], B[k=(lane>>4)*8+j][n=lane&15],
// C/D row=(lane>>4)*4+reg, col=lane&15.
template <int NM, int NX, int RELU>
__global__ __launch_bounds__(256) void lin_kernel(
    const float* __restrict__ m0, const float* __restrict__ m1,
    const float* __restrict__ x,
    const float* __restrict__ Wm0, const float* __restrict__ Wm1,
    const float* __restrict__ Wx0, const float* __restrict__ Wx1,
    const float* __restrict__ bias0, const float* __restrict__ bias1,
    float* __restrict__ out, int nrows) {
    const int lane = threadIdx.x & 63;
    const int wave = threadIdx.x >> 6;
    const int row0 = blockIdx.x * 64 + wave * 16;
    if (row0 >= nrows) return;
    const int r = lane & 15;
    const int q = lane >> 4;

    short8 wm0f[2][4], wm1f[2][4], wx0f[2][4], wx1f[2][4];
#pragma unroll
    for (int ks = 0; ks < 2; ks++) {
#pragma unroll
        for (int t = 0; t < 4; t++) {
            int col = t * 16 + r;
            int k0 = ks * 32 + q * 8;
#pragma unroll
            for (int j = 0; j < 8; j++) {
                int widx = (k0 + j) * 64 + col;
                if (NM >= 1) wm0f[ks][t][j] = f2bs(Wm0[widx]);
                if (NM >= 2) wm1f[ks][t][j] = f2bs(Wm1[widx]);
                if (NX >= 1) wx0f[ks][t][j] = f2bs(Wx0[widx]);
                if (NX >= 2) wx1f[ks][t][j] = f2bs(Wx1[widx]);
            }
        }
    }

    f32x4 acc[4];
#pragma unroll
    for (int t = 0; t < 4; t++) {
        float bv = bias0[t * 16 + r];
        if (bias1) bv += bias1[t * 16 + r];
        acc[t][0] = bv; acc[t][1] = bv; acc[t][2] = bv; acc[t][3] = bv;
    }

    const int arow = row0 + r;
    const bool avalid = arow < nrows;

    if (NM >= 1) {
#pragma unroll
        for (int ks = 0; ks < 2; ks++) {
            short8 af;
            if (avalid) {
                const float* p = m0 + (size_t)arow * 64 + q * 8 + ks * 32;
#pragma unroll
                for (int j = 0; j < 8; j++) af[j] = f2bs(p[j]);
            } else {
#pragma unroll
                for (int j = 0; j < 8; j++) af[j] = 0;
            }
#pragma unroll
            for (int t = 0; t < 4; t++)
                acc[t] = __builtin_amdgcn_mfma_f32_16x16x32_bf16(af, wm0f[ks][t], acc[t], 0, 0, 0);
        }
    }
    if (NM >= 2) {
#pragma unroll
        for (int ks = 0; ks < 2; ks++) {
            short8 af;
            if (avalid) {
                const float* p = m1 + (size_t)arow * 64 + q * 8 + ks * 32;
#pragma unroll
                for (int j = 0; j < 8; j++) af[j] = f2bs(p[j]);
            } else {
#pragma unroll
                for (int j = 0; j < 8; j++) af[j] = 0;
            }
#pragma unroll
            for (int t = 0; t < 4; t++)
                acc[t] = __builtin_amdgcn_mfma_f32_16x16x32_bf16(af, wm1f[ks][t], acc[t], 0, 0, 0);
        }
    }

    if (NX >= 1) {
#pragma unroll
        for (int ks = 0; ks < 2; ks++) {
            short8 xf;
            if (avalid) {
                const float* p = x + (size_t)arow * 64 + q * 8 + ks * 32;
#pragma unroll
                for (int j = 0; j < 8; j++) xf[j] = f2bs(p[j]);
            } else {
#pragma unroll
                for (int j = 0; j < 8; j++) xf[j] = 0;
            }
#pragma unroll
            for (int t = 0; t < 4; t++)
                acc[t] = __builtin_amdgcn_mfma_f32_16x16x32_bf16(xf, wx0f[ks][t], acc[t], 0, 0, 0);
            if (NX >= 2) {
#pragma unroll
                for (int t = 0; t < 4; t++)
                    acc[t] = __builtin_amdgcn_mfma_f32_16x16x32_bf16(xf, wx1f[ks][t], acc[t], 0, 0, 0);
            }
        }
    }

#pragma unroll
    for (int t = 0; t < 4; t++) {
#pragma unroll
        for (int rr = 0; rr < 4; rr++) {
            int row = row0 + q * 4 + rr;
            if (row < nrows) {
                float v = acc[t][rr];
                if (RELU) v = fmaxf(v, 0.0f);
                out[(size_t)row * 64 + t * 16 + r] = v;
            }
        }
    }
}

// ---------------- launch ----------------
extern "C" void kernel_launch(void* const* d_in, const int* in_sizes, int n_in,
                              void* d_out, int out_size, void* d_ws, size_t ws_size,
                              hipStream_t stream) {
    const float* xA_in = (const float*)d_in[0];
    const float* xB_in = (const float*)d_in[1];
    const float* Wn = (const float*)d_in[2];
    const float* Wr = (const float*)d_in[3];
    const float* b = (const float*)d_in[4];
    const float* W_out = (const float*)d_in[5];
    const float* b_out = (const float*)d_in[6];
    const int* src0 = (const int*)d_in[7];
    const int* dst0 = (const int*)d_in[8];
    const int* src1 = (const int*)d_in[9];
    const int* dst1 = (const int*)d_in[10];
    const int* src2 = (const int*)d_in[11];
    const int* dst2 = (const int*)d_in[12];

    const int NA = in_sizes[0] / 64;
    const int NB = in_sizes[1] / 64;
    const int E = in_sizes[7];
    const int M = NB + NA + NA;           // concatenated dst-space size
    const int goff0 = 0, goff1 = NB, goff2 = NB + NA;

    // ---- workspace layout (floats first, then ints) ----
    float* mean0 = (float*)d_ws;                        // [NA*64] (>=NB*64 too)
    float* mean1 = mean0 + (size_t)NA * 64;             // [NA*64]
    float* xA0  = mean1 + (size_t)NA * 64;              // [NA*64]
    float* xB0  = xA0 + (size_t)NA * 64;                // [NB*64]
    int* cnt    = (int*)(xB0 + (size_t)NB * 64);        // [M]
    int* cursor = cnt + M;                              // [M]
    int* off    = cursor + M;                           // [M+1]
    int* part   = off + (M + 1);                        // [<=1024]
    int* colidx = part + 1024;                          // [3*E]

    const int eBlocks = (E + 255) / 256;
    const int G = (M + 1023) / 1024;                    // scan partial blocks (<=1024)

    // ---- CSR build (once; graph static across layers) ----
    hipMemsetAsync(cnt, 0, (size_t)(2 * M) * 4, stream);   // cnt + cursor
    count_kernel<<<eBlocks, 256, 0, stream>>>(dst0, cnt, goff0, E);
    count_kernel<<<eBlocks, 256, 0, stream>>>(dst1, cnt, goff1, E);
    count_kernel<<<eBlocks, 256, 0, stream>>>(dst2, cnt, goff2, E);
    scan_reduce<<<G, 256, 0, stream>>>(cnt, M, part);
    scan_part<<<1, 1024, 0, stream>>>(part, G);
    scan_final<<<G, 256, 0, stream>>>(cnt, M, part, off);
    fill_kernel<<<eBlocks, 256, 0, stream>>>(src0, dst0, off, cursor, colidx, goff0, E);
    fill_kernel<<<eBlocks, 256, 0, stream>>>(src1, dst1, off, cursor, colidx, goff1, E);
    fill_kernel<<<eBlocks, 256, 0, stream>>>(src2, dst2, off, cursor, colidx, goff2, E);

    const float* xA = xA_in;
    const float* xB = xB_in;
    for (int l = 0; l < 2; l++) {
        float* xAn = (l == 0) ? xA0 : (float*)d_out;
        float* xBn = (l == 0) ? xB0 : ((float*)d_out + (size_t)NA * 64);

        // ---- B phase: new_B = mean(A->B) @ Wn[l,0] + x_B @ Wr[l,0] + b[l,0]
        gather_mean<<<(NB + 3) / 4, 256, 0, stream>>>(xA, colidx, off, goff0, mean0, NB);
        lin_kernel<1, 1, 0><<<(NB + 63) / 64, 256, 0, stream>>>(
            mean0, nullptr, xB,
            Wn + (size_t)(l * 3 + 0) * 4096, nullptr,
            Wr + (size_t)(l * 3 + 0) * 4096, nullptr,
            b + (size_t)(l * 3 + 0) * 64, nullptr, xBn, NB);

        // ---- A phase: new_A = mean(B->A)@Wn[l,1] + mean(A->A)@Wn[l,2]
        //               + x_A@(Wr[l,1]) + x_A@(Wr[l,2]) + b[l,1] + b[l,2]
        gather_mean<<<(NA + 3) / 4, 256, 0, stream>>>(xB, colidx, off, goff1, mean0, NA);
        gather_mean<<<(NA + 3) / 4, 256, 0, stream>>>(xA, colidx, off, goff2, mean1, NA);
        lin_kernel<2, 2, 0><<<(NA + 63) / 64, 256, 0, stream>>>(
            mean0, mean1, xA,
            Wn + (size_t)(l * 3 + 1) * 4096, Wn + (size_t)(l * 3 + 2) * 4096,
            Wr + (size_t)(l * 3 + 1) * 4096, Wr + (size_t)(l * 3 + 2) * 4096,
            b + (size_t)(l * 3 + 1) * 64, b + (size_t)(l * 3 + 2) * 64, xAn, NA);

        xA = xAn;
        xB = xBn;
    }

    // head: out = relu(x @ W_out + b_out), in place on d_out
    lin_kernel<0, 1, 1><<<(NA + 63) / 64, 256, 0, stream>>>(
        nullptr, nullptr, xA,
        nullptr, nullptr, W_out, nullptr, b_out, nullptr, (float*)d_out, NA);
    lin_kernel<0, 1, 1><<<(NB + 63) / 64, 256, 0, stream>>>(
        nullptr, nullptr, xB,
        nullptr, nullptr, W_out, nullptr, b_out, nullptr,
        (float*)d_out + (size_t)NA * 64, NB);
}

// Round 4
// 877.846 us; speedup vs baseline: 3.9214x; 1.2092x over previous
//
#include <hip/hip_runtime.h>
#include <hip/hip_bf16.h>

typedef __bf16 bf16_t;
typedef unsigned short u16;
typedef short short8 __attribute__((ext_vector_type(8)));
typedef float f32x4 __attribute__((ext_vector_type(4)));

__device__ inline short f2bs(float v) {
    bf16_t h = (bf16_t)v;
    return __builtin_bit_cast(short, h);
}
__device__ inline float bs2f(u16 s) {
    return (float)__builtin_bit_cast(bf16_t, (short)s);
}

// ---------------- feature f32 -> bf16 conversion ----------------
__global__ __launch_bounds__(256) void cvt_kernel(const float* __restrict__ in,
                                                  u16* __restrict__ out, int n4) {
    int i = blockIdx.x * 256 + threadIdx.x;
    if (i >= n4) return;
    float4 v = ((const float4*)in)[i];
    u16 o[4];
    o[0] = (u16)f2bs(v.x); o[1] = (u16)f2bs(v.y);
    o[2] = (u16)f2bs(v.z); o[3] = (u16)f2bs(v.w);
    *(uint2*)(out + (size_t)i * 4) = *(uint2*)o;
}

// ---------------- weight convert + transpose (13 mats of 64x64) ----------------
// wh[mat][n*64+k] = bf16(W[mat][k*64+n]); mats: Wn(0..5), Wr(6..11), W_out(12)
__global__ __launch_bounds__(256) void wt_kernel(const float* __restrict__ Wn,
                                                 const float* __restrict__ Wr,
                                                 const float* __restrict__ Wout,
                                                 u16* __restrict__ wh) {
    int mat = blockIdx.x;
    const float* src = (mat < 6) ? (Wn + (size_t)mat * 4096)
                     : (mat < 12) ? (Wr + (size_t)(mat - 6) * 4096)
                                  : Wout;
    u16* dstp = wh + (size_t)mat * 4096;
    for (int i = threadIdx.x; i < 4096; i += 256) {
        int k = i >> 6, n = i & 63;
        dstp[n * 64 + k] = (u16)f2bs(src[i]);
    }
}

// ---------------- CSR build ----------------
__global__ __launch_bounds__(256) void count_all(const int* __restrict__ d0,
                                                 const int* __restrict__ d1,
                                                 const int* __restrict__ d2,
                                                 int* __restrict__ cnt,
                                                 int NB, int NA, int E) {
    int i = blockIdx.x * 256 + threadIdx.x;
    if (i >= 3 * E) return;
    int g;
    if (i < E) g = d0[i];
    else if (i < 2 * E) g = NB + d1[i - E];
    else g = NB + NA + d2[i - 2 * E];
    atomicAdd(&cnt[g], 1);
}

__global__ __launch_bounds__(256) void scan_reduce(const int* __restrict__ cnt, int n,
                                                   int* __restrict__ part) {
    __shared__ int sdata[256];
    int base = blockIdx.x * 1024;
    int s = 0;
    for (int j = threadIdx.x; j < 1024; j += 256) {
        int i = base + j;
        s += (i < n) ? cnt[i] : 0;
    }
    sdata[threadIdx.x] = s;
    __syncthreads();
    for (int off = 128; off > 0; off >>= 1) {
        if (threadIdx.x < off) sdata[threadIdx.x] += sdata[threadIdx.x + off];
        __syncthreads();
    }
    if (threadIdx.x == 0) part[blockIdx.x] = sdata[0];
}

__global__ __launch_bounds__(1024) void scan_part(int* __restrict__ part, int G) {
    __shared__ int sdata[1024];
    int tid = threadIdx.x;
    sdata[tid] = (tid < G) ? part[tid] : 0;
    __syncthreads();
    for (int off = 1; off < 1024; off <<= 1) {
        int t = (tid >= off) ? sdata[tid - off] : 0;
        __syncthreads();
        sdata[tid] += t;
        __syncthreads();
    }
    if (tid < G) part[tid] = (tid == 0) ? 0 : sdata[tid - 1];
}

__global__ __launch_bounds__(256) void scan_final(const int* __restrict__ cnt, int n,
                                                  const int* __restrict__ partscan,
                                                  int* __restrict__ off) {
    __shared__ int sdata[256];
    int base = blockIdx.x * 1024;
    int tid = threadIdx.x;
    int v[4];
    int s = 0;
#pragma unroll
    for (int j = 0; j < 4; j++) {
        int i = base + tid * 4 + j;
        v[j] = s;
        s += (i < n) ? cnt[i] : 0;
    }
    sdata[tid] = s;
    __syncthreads();
    for (int offd = 1; offd < 256; offd <<= 1) {
        int t = (tid >= offd) ? sdata[tid - offd] : 0;
        __syncthreads();
        sdata[tid] += t;
        __syncthreads();
    }
    int thread_excl = (tid == 0) ? 0 : sdata[tid - 1];
    int blockoff = partscan[blockIdx.x];
#pragma unroll
    for (int j = 0; j < 4; j++) {
        int i = base + tid * 4 + j;
        if (i < n) off[i] = blockoff + thread_excl + v[j];
    }
    if (blockIdx.x == gridDim.x - 1 && tid == 255) off[n] = blockoff + sdata[255];
}

__global__ __launch_bounds__(256) void fill_all(const int* __restrict__ s0, const int* __restrict__ d0,
                                                const int* __restrict__ s1, const int* __restrict__ d1,
                                                const int* __restrict__ s2, const int* __restrict__ d2,
                                                const int* __restrict__ off, int* __restrict__ cursor,
                                                int* __restrict__ colidx, int NB, int NA, int E) {
    int i = blockIdx.x * 256 + threadIdx.x;
    if (i >= 3 * E) return;
    int s, g;
    if (i < E) { s = s0[i]; g = d0[i]; }
    else if (i < 2 * E) { s = s1[i - E]; g = NB + d1[i - E]; }
    else { s = s2[i - 2 * E]; g = NB + NA + d2[i - 2 * E]; }
    int pos = atomicAdd(&cursor[g], 1);
    colidx[off[g] + pos] = s;
}

// ---------------- gather-mean, all 3 graphs in one launch (bf16) ----------------
// one wave per dst row; lane-halves process alternating edges (2 feats/lane),
// cross-half reduce via shfl_xor(32).
__global__ __launch_bounds__(256) void gather_all(const u16* __restrict__ xAh,
                                                  const u16* __restrict__ xBh,
                                                  const int* __restrict__ colidx,
                                                  const int* __restrict__ off,
                                                  u16* __restrict__ meanB,
                                                  u16* __restrict__ meanA1,
                                                  u16* __restrict__ meanA2,
                                                  int NB, int NA) {
    int wid = (blockIdx.x * 256 + threadIdx.x) >> 6;
    int lane = threadIdx.x & 63;
    int M = NB + 2 * NA;
    if (wid >= M) return;
    const u16* tab;
    u16* outp;
    int orow;
    if (wid < NB) { tab = xAh; outp = meanB; orow = wid; }
    else if (wid < NB + NA) { tab = xBh; outp = meanA1; orow = wid - NB; }
    else { tab = xAh; outp = meanA2; orow = wid - NB - NA; }

    int s0 = off[wid], s1 = off[wid + 1];
    int half = lane >> 5, fl = lane & 31;
    float ax = 0.f, ay = 0.f, bx = 0.f, by = 0.f;
    int e = s0 + half;
    for (; e + 2 < s1; e += 4) {
        int c0 = colidx[e], c1 = colidx[e + 2];
        ushort2 u0 = *(const ushort2*)(tab + (size_t)c0 * 64 + fl * 2);
        ushort2 u1 = *(const ushort2*)(tab + (size_t)c1 * 64 + fl * 2);
        ax += bs2f(u0.x); ay += bs2f(u0.y);
        bx += bs2f(u1.x); by += bs2f(u1.y);
    }
    for (; e < s1; e += 2) {
        int c = colidx[e];
        ushort2 u = *(const ushort2*)(tab + (size_t)c * 64 + fl * 2);
        ax += bs2f(u.x); ay += bs2f(u.y);
    }
    ax += bx; ay += by;
    ax += __shfl_xor(ax, 32);
    ay += __shfl_xor(ay, 32);
    if (half == 0) {
        float inv = 1.0f / fmaxf((float)(s1 - s0), 1.0f);
        u16 o[2];
        o[0] = (u16)f2bs(ax * inv);
        o[1] = (u16)f2bs(ay * inv);
        *(unsigned int*)(outp + (size_t)orow * 64 + fl * 2) = *(unsigned int*)o;
    }
}

// ---------------- fused linear (bf16 in, MFMA, bf16 or f32 out) ----------------
// Layouts: A[m=lane&15][k=(lane>>4)*8+j], B[k][n=lane&15] (weights pre-transposed
// so fragments are contiguous short8), C/D row=(lane>>4)*4+reg, col=lane&15.
template <int NM, int NX, int RELU, int OUTF32>
__global__ __launch_bounds__(256) void lin_kernel(
    const u16* __restrict__ m0, const u16* __restrict__ m1,
    const u16* __restrict__ x,
    const u16* __restrict__ Wm0t, const u16* __restrict__ Wm1t,
    const u16* __restrict__ Wx0t, const u16* __restrict__ Wx1t,
    const float* __restrict__ bias0, const float* __restrict__ bias1,
    void* __restrict__ outv, int nrows) {
    const int lane = threadIdx.x & 63;
    const int wave = threadIdx.x >> 6;
    const int row0 = blockIdx.x * 64 + wave * 16;
    if (row0 >= nrows) return;
    const int r = lane & 15;
    const int q = lane >> 4;

    // weight fragments: contiguous short8 at Wt + col*64 + ks*32 + q*8
    short8 wm0f[2][4], wm1f[2][4], wx0f[2][4], wx1f[2][4];
#pragma unroll
    for (int ks = 0; ks < 2; ks++) {
#pragma unroll
        for (int t = 0; t < 4; t++) {
            size_t widx = (size_t)(t * 16 + r) * 64 + ks * 32 + q * 8;
            if (NM >= 1) wm0f[ks][t] = *(const short8*)(Wm0t + widx);
            if (NM >= 2) wm1f[ks][t] = *(const short8*)(Wm1t + widx);
            if (NX >= 1) wx0f[ks][t] = *(const short8*)(Wx0t + widx);
            if (NX >= 2) wx1f[ks][t] = *(const short8*)(Wx1t + widx);
        }
    }

    f32x4 acc[4];
#pragma unroll
    for (int t = 0; t < 4; t++) {
        float bv = bias0[t * 16 + r];
        if (bias1) bv += bias1[t * 16 + r];
        acc[t][0] = bv; acc[t][1] = bv; acc[t][2] = bv; acc[t][3] = bv;
    }

    const int arow = row0 + r;
    const bool avalid = arow < nrows;
    short8 zf;
#pragma unroll
    for (int j = 0; j < 8; j++) zf[j] = 0;

    if (NM >= 1) {
#pragma unroll
        for (int ks = 0; ks < 2; ks++) {
            short8 af = avalid ? *(const short8*)(m0 + (size_t)arow * 64 + ks * 32 + q * 8) : zf;
#pragma unroll
            for (int t = 0; t < 4; t++)
                acc[t] = __builtin_amdgcn_mfma_f32_16x16x32_bf16(af, wm0f[ks][t], acc[t], 0, 0, 0);
        }
    }
    if (NM >= 2) {
#pragma unroll
        for (int ks = 0; ks < 2; ks++) {
            short8 af = avalid ? *(const short8*)(m1 + (size_t)arow * 64 + ks * 32 + q * 8) : zf;
#pragma unroll
            for (int t = 0; t < 4; t++)
                acc[t] = __builtin_amdgcn_mfma_f32_16x16x32_bf16(af, wm1f[ks][t], acc[t], 0, 0, 0);
        }
    }
    if (NX >= 1) {
#pragma unroll
        for (int ks = 0; ks < 2; ks++) {
            short8 xf = avalid ? *(const short8*)(x + (size_t)arow * 64 + ks * 32 + q * 8) : zf;
#pragma unroll
            for (int t = 0; t < 4; t++)
                acc[t] = __builtin_amdgcn_mfma_f32_16x16x32_bf16(xf, wx0f[ks][t], acc[t], 0, 0, 0);
            if (NX >= 2) {
#pragma unroll
                for (int t = 0; t < 4; t++)
                    acc[t] = __builtin_amdgcn_mfma_f32_16x16x32_bf16(xf, wx1f[ks][t], acc[t], 0, 0, 0);
            }
        }
    }

#pragma unroll
    for (int t = 0; t < 4; t++) {
#pragma unroll
        for (int rr = 0; rr < 4; rr++) {
            int row = row0 + q * 4 + rr;
            if (row < nrows) {
                float v = acc[t][rr];
                if (RELU) v = fmaxf(v, 0.0f);
                if (OUTF32) ((float*)outv)[(size_t)row * 64 + t * 16 + r] = v;
                else ((u16*)outv)[(size_t)row * 64 + t * 16 + r] = (u16)f2bs(v);
            }
        }
    }
}

// ---------------- launch ----------------
extern "C" void kernel_launch(void* const* d_in, const int* in_sizes, int n_in,
                              void* d_out, int out_size, void* d_ws, size_t ws_size,
                              hipStream_t stream) {
    const float* xA_in = (const float*)d_in[0];
    const float* xB_in = (const float*)d_in[1];
    const float* Wn = (const float*)d_in[2];
    const float* Wr = (const float*)d_in[3];
    const float* b = (const float*)d_in[4];
    const float* W_out = (const float*)d_in[5];
    const float* b_out = (const float*)d_in[6];
    const int* src0 = (const int*)d_in[7];
    const int* dst0 = (const int*)d_in[8];
    const int* src1 = (const int*)d_in[9];
    const int* dst1 = (const int*)d_in[10];
    const int* src2 = (const int*)d_in[11];
    const int* dst2 = (const int*)d_in[12];

    const int NA = in_sizes[0] / 64;
    const int NB = in_sizes[1] / 64;
    const int E = in_sizes[7];
    const int M = NB + NA + NA;

    // ---- workspace layout ----
    u16* xAh[2]; u16* xBh[2];
    xAh[0] = (u16*)d_ws;
    xAh[1] = xAh[0] + (size_t)NA * 64;
    xBh[0] = xAh[1] + (size_t)NA * 64;
    xBh[1] = xBh[0] + (size_t)NB * 64;
    u16* meanB  = xBh[1] + (size_t)NB * 64;
    u16* meanA1 = meanB + (size_t)NB * 64;
    u16* meanA2 = meanA1 + (size_t)NA * 64;
    u16* wh     = meanA2 + (size_t)NA * 64;              // 13*4096 bf16
    int* cnt    = (int*)(wh + 13 * 4096);
    int* cursor = cnt + M;
    int* off    = cursor + M;
    int* part   = off + (M + 1);
    int* colidx = part + 1024;

    const int G = (M + 1023) / 1024;
    const int e3Blocks = (3 * E + 255) / 256;

    // ---- conversions ----
    cvt_kernel<<<(NA * 16 + 255) / 256, 256, 0, stream>>>(xA_in, xAh[0], NA * 16);
    cvt_kernel<<<(NB * 16 + 255) / 256, 256, 0, stream>>>(xB_in, xBh[0], NB * 16);
    wt_kernel<<<13, 256, 0, stream>>>(Wn, Wr, W_out, wh);

    // ---- CSR build (once) ----
    hipMemsetAsync(cnt, 0, (size_t)(2 * M) * 4, stream);
    count_all<<<e3Blocks, 256, 0, stream>>>(dst0, dst1, dst2, cnt, NB, NA, E);
    scan_reduce<<<G, 256, 0, stream>>>(cnt, M, part);
    scan_part<<<1, 1024, 0, stream>>>(part, G);
    scan_final<<<G, 256, 0, stream>>>(cnt, M, part, off);
    fill_all<<<e3Blocks, 256, 0, stream>>>(src0, dst0, src1, dst1, src2, dst2,
                                           off, cursor, colidx, NB, NA, E);

    // weight mats: Wn[l,e] -> wh + (l*3+e)*4096; Wr[l,e] -> wh + (6+l*3+e)*4096; Wout -> 12
    int p = 0;
    for (int l = 0; l < 2; l++) {
        gather_all<<<(M + 3) / 4, 256, 0, stream>>>(xAh[p], xBh[p], colidx, off,
                                                    meanB, meanA1, meanA2, NB, NA);
        lin_kernel<1, 1, 0, 0><<<(NB + 63) / 64, 256, 0, stream>>>(
            meanB, nullptr, xBh[p],
            wh + (size_t)(l * 3 + 0) * 4096, nullptr,
            wh + (size_t)(6 + l * 3 + 0) * 4096, nullptr,
            b + (size_t)(l * 3 + 0) * 64, nullptr, xBh[1 - p], NB);
        lin_kernel<2, 2, 0, 0><<<(NA + 63) / 64, 256, 0, stream>>>(
            meanA1, meanA2, xAh[p],
            wh + (size_t)(l * 3 + 1) * 4096, wh + (size_t)(l * 3 + 2) * 4096,
            wh + (size_t)(6 + l * 3 + 1) * 4096, wh + (size_t)(6 + l * 3 + 2) * 4096,
            b + (size_t)(l * 3 + 1) * 64, b + (size_t)(l * 3 + 2) * 64, xAh[1 - p], NA);
        p = 1 - p;
    }

    // head: relu(x @ W_out + b_out) -> f32 d_out
    lin_kernel<0, 1, 1, 1><<<(NA + 63) / 64, 256, 0, stream>>>(
        nullptr, nullptr, xAh[p],
        nullptr, nullptr, wh + (size_t)12 * 4096, nullptr,
        b_out, nullptr, (float*)d_out, NA);
    lin_kernel<0, 1, 1, 1><<<(NB + 63) / 64, 256, 0, stream>>>(
        nullptr, nullptr, xBh[p],
        nullptr, nullptr, wh + (size_t)12 * 4096, nullptr,
        b_out, nullptr, (float*)d_out + (size_t)NA * 64, NB);
}

// Round 5
// 654.479 us; speedup vs baseline: 5.2597x; 1.3413x over previous
//
#include <hip/hip_runtime.h>
#include <hip/hip_bf16.h>

typedef __bf16 bf16_t;
typedef unsigned short u16;
typedef short short8 __attribute__((ext_vector_type(8)));
typedef float f32x4 __attribute__((ext_vector_type(4)));

#define BSHIFT 9            // 512 dst-rows per bucket
#define TILE 8192

__device__ inline short f2bs(float v) {
    bf16_t h = (bf16_t)v;
    return __builtin_bit_cast(short, h);
}
__device__ inline float bs2f(u16 s) {
    return (float)__builtin_bit_cast(bf16_t, (short)s);
}

// ---------------- feature f32 -> bf16 conversion ----------------
__global__ __launch_bounds__(256) void cvt_kernel(const float* __restrict__ in,
                                                  u16* __restrict__ out, int n4) {
    int i = blockIdx.x * 256 + threadIdx.x;
    if (i >= n4) return;
    float4 v = ((const float4*)in)[i];
    u16 o[4];
    o[0] = (u16)f2bs(v.x); o[1] = (u16)f2bs(v.y);
    o[2] = (u16)f2bs(v.z); o[3] = (u16)f2bs(v.w);
    *(uint2*)(out + (size_t)i * 4) = *(uint2*)o;
}

// ---------------- weight convert + transpose (13 mats of 64x64) ----------------
__global__ __launch_bounds__(256) void wt_kernel(const float* __restrict__ Wn,
                                                 const float* __restrict__ Wr,
                                                 const float* __restrict__ Wout,
                                                 u16* __restrict__ wh) {
    int mat = blockIdx.x;
    const float* src = (mat < 6) ? (Wn + (size_t)mat * 4096)
                     : (mat < 12) ? (Wr + (size_t)(mat - 6) * 4096)
                                  : Wout;
    u16* dstp = wh + (size_t)mat * 4096;
    for (int i = threadIdx.x; i < 4096; i += 256) {
        int k = i >> 6, n = i & 63;
        dstp[n * 64 + k] = (u16)f2bs(src[i]);
    }
}

// ---------------- CSR build: bucketed multisplit ----------------
// phase 0: per-bucket edge counts (LDS hist, flush once per block)
__global__ __launch_bounds__(256) void bucket_count(const int* __restrict__ d0,
                                                    const int* __restrict__ d1,
                                                    const int* __restrict__ d2,
                                                    int* __restrict__ ghist,
                                                    int NB, int NA, int E, int total, int K) {
    __shared__ int h[1024];
    int tid = threadIdx.x;
    for (int i = tid; i < 1024; i += 256) h[i] = 0;
    __syncthreads();
    for (int i = blockIdx.x * 256 + tid; i < total; i += gridDim.x * 256) {
        int g;
        if (i < E) g = d0[i];
        else if (i < 2 * E) g = NB + d1[i - E];
        else g = NB + NA + d2[i - 2 * E];
        atomicAdd(&h[g >> BSHIFT], 1);
    }
    __syncthreads();
    for (int i = tid; i < K; i += 256)
        if (h[i]) atomicAdd(&ghist[i], h[i]);
}

// phase 0b: exclusive scan of K bucket totals (single block)
__global__ __launch_bounds__(256) void bucket_scan(const int* __restrict__ ghist,
                                                   int* __restrict__ bbase,
                                                   int* __restrict__ gcursor,
                                                   int K, int total) {
    __shared__ int ssum[256];
    int tid = threadIdx.x;
    int v[4]; int s = 0;
#pragma unroll
    for (int j = 0; j < 4; j++) {
        int i = tid * 4 + j;
        v[j] = s;
        s += (i < K) ? ghist[i] : 0;
    }
    ssum[tid] = s; __syncthreads();
    for (int off = 1; off < 256; off <<= 1) {
        int t = (tid >= off) ? ssum[tid - off] : 0; __syncthreads();
        ssum[tid] += t; __syncthreads();
    }
    int exc = tid ? ssum[tid - 1] : 0;
#pragma unroll
    for (int j = 0; j < 4; j++) {
        int i = tid * 4 + j;
        if (i < K) { bbase[i] = exc + v[j]; gcursor[i] = exc + v[j]; }
        exc += 0;
    }
    if (tid == 255) bbase[K] = total;
}

// phase 1: scatter (src,gid) pairs into bucket-contiguous order, LDS tile reorder
__global__ __launch_bounds__(256) void partition_kernel(
    const int* __restrict__ s0, const int* __restrict__ d0,
    const int* __restrict__ s1, const int* __restrict__ d1,
    const int* __restrict__ s2, const int* __restrict__ d2,
    int* __restrict__ gcursor, int2* __restrict__ pairs,
    int NB, int NA, int E, int total) {
    __shared__ int hist[1024];   // per-tile bucket counts, then tile-local excl scan
    __shared__ int gbase[1024];  // global base per bucket for this tile
    __shared__ int ssum[256];
    __shared__ int2 buf[TILE];   // 64 KB
    int tid = threadIdx.x;
    for (int tile = blockIdx.x * TILE; tile < total; tile += gridDim.x * TILE) {
        for (int i = tid; i < 1024; i += 256) hist[i] = 0;
        __syncthreads();
        int cnt = min(TILE, total - tile);
        int myg[32], mysrc[32], myrank[32];
#pragma unroll
        for (int j = 0; j < 32; j++) {
            int idx = tile + j * 256 + tid;
            int g = -1, s = 0;
            if (idx < total) {
                if (idx < E) { s = s0[idx]; g = d0[idx]; }
                else if (idx < 2 * E) { s = s1[idx - E]; g = NB + d1[idx - E]; }
                else { s = s2[idx - 2 * E]; g = NB + NA + d2[idx - 2 * E]; }
            }
            myg[j] = g; mysrc[j] = s;
            if (g >= 0) myrank[j] = atomicAdd(&hist[g >> BSHIFT], 1);
        }
        __syncthreads();
        int l[4]; int base4 = tid * 4; int ts = 0;
#pragma unroll
        for (int j = 0; j < 4; j++) { l[j] = hist[base4 + j]; ts += l[j]; }
        ssum[tid] = ts; __syncthreads();
        for (int off = 1; off < 256; off <<= 1) {
            int t = (tid >= off) ? ssum[tid - off] : 0; __syncthreads();
            ssum[tid] += t; __syncthreads();
        }
        int exc = tid ? ssum[tid - 1] : 0;
#pragma unroll
        for (int j = 0; j < 4; j++) {
            hist[base4 + j] = exc;
            if (l[j]) gbase[base4 + j] = atomicAdd(&gcursor[base4 + j], l[j]);
            exc += l[j];
        }
        __syncthreads();
#pragma unroll
        for (int j = 0; j < 32; j++) {
            if (myg[j] >= 0) {
                int bkt = myg[j] >> BSHIFT;
                buf[hist[bkt] + myrank[j]] = make_int2(mysrc[j], myg[j]);
            }
        }
        __syncthreads();
        for (int i = tid; i < cnt; i += 256) {
            int2 p = buf[i];
            int bkt = p.y >> BSHIFT;
            pairs[gbase[bkt] + (i - hist[bkt])] = p;
        }
        __syncthreads();
    }
}

// phase 2: one block per bucket; row counts/cursors in LDS; emit off[] + colidx
__global__ __launch_bounds__(256) void bucket_fill(const int2* __restrict__ pairs,
                                                   const int* __restrict__ bbase,
                                                   int* __restrict__ off,
                                                   int* __restrict__ colidx,
                                                   int M, int K) {
    int b = blockIdx.x;
    int gb = b << BSHIFT;
    __shared__ int cnt[512], cur[512], ssum[256];
    int tid = threadIdx.x;
    int p0 = bbase[b], p1 = bbase[b + 1];
    cnt[tid] = 0; cnt[tid + 256] = 0;
    __syncthreads();
    for (int e = p0 + tid; e < p1; e += 256)
        atomicAdd(&cnt[pairs[e].y - gb], 1);
    __syncthreads();
    int l0 = cnt[2 * tid], l1 = cnt[2 * tid + 1];
    ssum[tid] = l0 + l1; __syncthreads();
    for (int o = 1; o < 256; o <<= 1) {
        int t = (tid >= o) ? ssum[tid - o] : 0; __syncthreads();
        ssum[tid] += t; __syncthreads();
    }
    int exc = tid ? ssum[tid - 1] : 0;
    int e0 = exc, e1 = exc + l0;
    cur[2 * tid] = e0; cur[2 * tid + 1] = e1;
    int g0 = gb + 2 * tid, g1 = gb + 2 * tid + 1;
    if (g0 <= M) off[g0] = p0 + e0;
    if (g1 <= M) off[g1] = p0 + e1;
    if (b == K - 1 && tid == 0) off[M] = p1;
    __syncthreads();
    for (int e = p0 + tid; e < p1; e += 256) {
        int2 p = pairs[e];
        int pos = atomicAdd(&cur[p.y - gb], 1);
        colidx[p0 + pos] = p.x;
    }
}

// ---------------- gather-mean, all 3 graphs in one launch (bf16) ----------------
__global__ __launch_bounds__(256) void gather_all(const u16* __restrict__ xAh,
                                                  const u16* __restrict__ xBh,
                                                  const int* __restrict__ colidx,
                                                  const int* __restrict__ off,
                                                  u16* __restrict__ meanB,
                                                  u16* __restrict__ meanA1,
                                                  u16* __restrict__ meanA2,
                                                  int NB, int NA) {
    int wid = (blockIdx.x * 256 + threadIdx.x) >> 6;
    int lane = threadIdx.x & 63;
    int M = NB + 2 * NA;
    if (wid >= M) return;
    const u16* tab;
    u16* outp;
    int orow;
    if (wid < NB) { tab = xAh; outp = meanB; orow = wid; }
    else if (wid < NB + NA) { tab = xBh; outp = meanA1; orow = wid - NB; }
    else { tab = xAh; outp = meanA2; orow = wid - NB - NA; }

    int s0 = off[wid], s1 = off[wid + 1];
    int half = lane >> 5, fl = lane & 31;
    float ax = 0.f, ay = 0.f, bx = 0.f, by = 0.f;
    int e = s0 + half;
    for (; e + 2 < s1; e += 4) {
        int c0 = colidx[e], c1 = colidx[e + 2];
        ushort2 u0 = *(const ushort2*)(tab + (size_t)c0 * 64 + fl * 2);
        ushort2 u1 = *(const ushort2*)(tab + (size_t)c1 * 64 + fl * 2);
        ax += bs2f(u0.x); ay += bs2f(u0.y);
        bx += bs2f(u1.x); by += bs2f(u1.y);
    }
    for (; e < s1; e += 2) {
        int c = colidx[e];
        ushort2 u = *(const ushort2*)(tab + (size_t)c * 64 + fl * 2);
        ax += bs2f(u.x); ay += bs2f(u.y);
    }
    ax += bx; ay += by;
    ax += __shfl_xor(ax, 32);
    ay += __shfl_xor(ay, 32);
    if (half == 0) {
        float inv = 1.0f / fmaxf((float)(s1 - s0), 1.0f);
        u16 o[2];
        o[0] = (u16)f2bs(ax * inv);
        o[1] = (u16)f2bs(ay * inv);
        *(unsigned int*)(outp + (size_t)orow * 64 + fl * 2) = *(unsigned int*)o;
    }
}

// ---------------- fused linear (bf16 in, MFMA, bf16 or f32 out) ----------------
template <int NM, int NX, int RELU, int OUTF32>
__global__ __launch_bounds__(256) void lin_kernel(
    const u16* __restrict__ m0, const u16* __restrict__ m1,
    const u16* __restrict__ x,
    const u16* __restrict__ Wm0t, const u16* __restrict__ Wm1t,
    const u16* __restrict__ Wx0t, const u16* __restrict__ Wx1t,
    const float* __restrict__ bias0, const float* __restrict__ bias1,
    void* __restrict__ outv, int nrows) {
    const int lane = threadIdx.x & 63;
    const int wave = threadIdx.x >> 6;
    const int row0 = blockIdx.x * 64 + wave * 16;
    if (row0 >= nrows) return;
    const int r = lane & 15;
    const int q = lane >> 4;

    short8 wm0f[2][4], wm1f[2][4], wx0f[2][4], wx1f[2][4];
#pragma unroll
    for (int ks = 0; ks < 2; ks++) {
#pragma unroll
        for (int t = 0; t < 4; t++) {
            size_t widx = (size_t)(t * 16 + r) * 64 + ks * 32 + q * 8;
            if (NM >= 1) wm0f[ks][t] = *(const short8*)(Wm0t + widx);
            if (NM >= 2) wm1f[ks][t] = *(const short8*)(Wm1t + widx);
            if (NX >= 1) wx0f[ks][t] = *(const short8*)(Wx0t + widx);
            if (NX >= 2) wx1f[ks][t] = *(const short8*)(Wx1t + widx);
        }
    }

    f32x4 acc[4];
#pragma unroll
    for (int t = 0; t < 4; t++) {
        float bv = bias0[t * 16 + r];
        if (bias1) bv += bias1[t * 16 + r];
        acc[t][0] = bv; acc[t][1] = bv; acc[t][2] = bv; acc[t][3] = bv;
    }

    const int arow = row0 + r;
    const bool avalid = arow < nrows;
    short8 zf;
#pragma unroll
    for (int j = 0; j < 8; j++) zf[j] = 0;

    if (NM >= 1) {
#pragma unroll
        for (int ks = 0; ks < 2; ks++) {
            short8 af = avalid ? *(const short8*)(m0 + (size_t)arow * 64 + ks * 32 + q * 8) : zf;
#pragma unroll
            for (int t = 0; t < 4; t++)
                acc[t] = __builtin_amdgcn_mfma_f32_16x16x32_bf16(af, wm0f[ks][t], acc[t], 0, 0, 0);
        }
    }
    if (NM >= 2) {
#pragma unroll
        for (int ks = 0; ks < 2; ks++) {
            short8 af = avalid ? *(const short8*)(m1 + (size_t)arow * 64 + ks * 32 + q * 8) : zf;
#pragma unroll
            for (int t = 0; t < 4; t++)
                acc[t] = __builtin_amdgcn_mfma_f32_16x16x32_bf16(af, wm1f[ks][t], acc[t], 0, 0, 0);
        }
    }
    if (NX >= 1) {
#pragma unroll
        for (int ks = 0; ks < 2; ks++) {
            short8 xf = avalid ? *(const short8*)(x + (size_t)arow * 64 + ks * 32 + q * 8) : zf;
#pragma unroll
            for (int t = 0; t < 4; t++)
                acc[t] = __builtin_amdgcn_mfma_f32_16x16x32_bf16(xf, wx0f[ks][t], acc[t], 0, 0, 0);
            if (NX >= 2) {
#pragma unroll
                for (int t = 0; t < 4; t++)
                    acc[t] = __builtin_amdgcn_mfma_f32_16x16x32_bf16(xf, wx1f[ks][t], acc[t], 0, 0, 0);
            }
        }
    }

#pragma unroll
    for (int t = 0; t < 4; t++) {
#pragma unroll
        for (int rr = 0; rr < 4; rr++) {
            int row = row0 + q * 4 + rr;
            if (row < nrows) {
                float v = acc[t][rr];
                if (RELU) v = fmaxf(v, 0.0f);
                if (OUTF32) ((float*)outv)[(size_t)row * 64 + t * 16 + r] = v;
                else ((u16*)outv)[(size_t)row * 64 + t * 16 + r] = (u16)f2bs(v);
            }
        }
    }
}

// ---------------- launch ----------------
extern "C" void kernel_launch(void* const* d_in, const int* in_sizes, int n_in,
                              void* d_out, int out_size, void* d_ws, size_t ws_size,
                              hipStream_t stream) {
    const float* xA_in = (const float*)d_in[0];
    const float* xB_in = (const float*)d_in[1];
    const float* Wn = (const float*)d_in[2];
    const float* Wr = (const float*)d_in[3];
    const float* b = (const float*)d_in[4];
    const float* W_out = (const float*)d_in[5];
    const float* b_out = (const float*)d_in[6];
    const int* src0 = (const int*)d_in[7];
    const int* dst0 = (const int*)d_in[8];
    const int* src1 = (const int*)d_in[9];
    const int* dst1 = (const int*)d_in[10];
    const int* src2 = (const int*)d_in[11];
    const int* dst2 = (const int*)d_in[12];

    const int NA = in_sizes[0] / 64;
    const int NB = in_sizes[1] / 64;
    const int E = in_sizes[7];
    const int M = NB + NA + NA;
    const int total = 3 * E;
    const int K = (M + 511) >> BSHIFT;     // buckets of 512 rows (K <= 1024)

    // ---- workspace layout ----
    u16* xAh[2]; u16* xBh[2];
    xAh[0] = (u16*)d_ws;
    xAh[1] = xAh[0] + (size_t)NA * 64;
    xBh[0] = xAh[1] + (size_t)NA * 64;
    xBh[1] = xBh[0] + (size_t)NB * 64;
    u16* meanB  = xBh[1] + (size_t)NB * 64;
    u16* meanA1 = meanB + (size_t)NB * 64;
    u16* meanA2 = meanA1 + (size_t)NA * 64;
    u16* wh     = meanA2 + (size_t)NA * 64;              // 13*4096 bf16
    int* ghist  = (int*)(wh + 13 * 4096);                // [1024]
    int* bbase  = ghist + 1024;                          // [K+1]
    int* gcursor= bbase + 1025;                          // [1024]
    int* off    = gcursor + 1024;                        // [M+1]
    int* colidx = off + (M + 1);                         // [3E]
    // pairs aliases the means region (dead until gathers run; CSR build precedes)
    int2* pairs = (int2*)meanB;                          // [3E] (38.4MB region >= 28.8MB)

    // ---- conversions ----
    cvt_kernel<<<(NA * 16 + 255) / 256, 256, 0, stream>>>(xA_in, xAh[0], NA * 16);
    cvt_kernel<<<(NB * 16 + 255) / 256, 256, 0, stream>>>(xB_in, xBh[0], NB * 16);
    wt_kernel<<<13, 256, 0, stream>>>(Wn, Wr, W_out, wh);

    // ---- CSR build: bucketed multisplit ----
    hipMemsetAsync(ghist, 0, 1024 * 4, stream);
    bucket_count<<<512, 256, 0, stream>>>(dst0, dst1, dst2, ghist, NB, NA, E, total, K);
    bucket_scan<<<1, 256, 0, stream>>>(ghist, bbase, gcursor, K, total);
    int ntiles = (total + TILE - 1) / TILE;
    partition_kernel<<<ntiles, 256, 0, stream>>>(src0, dst0, src1, dst1, src2, dst2,
                                                 gcursor, pairs, NB, NA, E, total);
    bucket_fill<<<K, 256, 0, stream>>>(pairs, bbase, off, colidx, M, K);

    int p = 0;
    for (int l = 0; l < 2; l++) {
        gather_all<<<(M + 3) / 4, 256, 0, stream>>>(xAh[p], xBh[p], colidx, off,
                                                    meanB, meanA1, meanA2, NB, NA);
        lin_kernel<1, 1, 0, 0><<<(NB + 63) / 64, 256, 0, stream>>>(
            meanB, nullptr, xBh[p],
            wh + (size_t)(l * 3 + 0) * 4096, nullptr,
            wh + (size_t)(6 + l * 3 + 0) * 4096, nullptr,
            b + (size_t)(l * 3 + 0) * 64, nullptr, xBh[1 - p], NB);
        lin_kernel<2, 2, 0, 0><<<(NA + 63) / 64, 256, 0, stream>>>(
            meanA1, meanA2, xAh[p],
            wh + (size_t)(l * 3 + 1) * 4096, wh + (size_t)(l * 3 + 2) * 4096,
            wh + (size_t)(6 + l * 3 + 1) * 4096, wh + (size_t)(6 + l * 3 + 2) * 4096,
            b + (size_t)(l * 3 + 1) * 64, b + (size_t)(l * 3 + 2) * 64, xAh[1 - p], NA);
        p = 1 - p;
    }

    // head: relu(x @ W_out + b_out) -> f32 d_out
    lin_kernel<0, 1, 1, 1><<<(NA + 63) / 64, 256, 0, stream>>>(
        nullptr, nullptr, xAh[p],
        nullptr, nullptr, wh + (size_t)12 * 4096, nullptr,
        b_out, nullptr, (float*)d_out, NA);
    lin_kernel<0, 1, 1, 1><<<(NB + 63) / 64, 256, 0, stream>>>(
        nullptr, nullptr, xBh[p],
        nullptr, nullptr, wh + (size_t)12 * 4096, nullptr,
        b_out, nullptr, (float*)d_out + (size_t)NA * 64, NB);
}

// Round 6
// 594.072 us; speedup vs baseline: 5.7946x; 1.1017x over previous
//
#include <hip/hip_runtime.h>
#include <hip/hip_bf16.h>

typedef __bf16 bf16_t;
typedef unsigned short u16;
typedef short short8 __attribute__((ext_vector_type(8)));
typedef float f32x4 __attribute__((ext_vector_type(4)));

#define BSHIFT 10           // 1024 dst-rows per bucket
#define TILE 8192

__device__ inline short f2bs(float v) {
    bf16_t h = (bf16_t)v;
    return __builtin_bit_cast(short, h);
}
__device__ inline float uif(unsigned u) { return __builtin_bit_cast(float, u); }

// ---------------- feature f32 -> bf16 conversion ----------------
__global__ __launch_bounds__(256) void cvt_kernel(const float* __restrict__ in,
                                                  u16* __restrict__ out, int n4) {
    int i = blockIdx.x * 256 + threadIdx.x;
    if (i >= n4) return;
    float4 v = ((const float4*)in)[i];
    u16 o[4];
    o[0] = (u16)f2bs(v.x); o[1] = (u16)f2bs(v.y);
    o[2] = (u16)f2bs(v.z); o[3] = (u16)f2bs(v.w);
    *(uint2*)(out + (size_t)i * 4) = *(uint2*)o;
}

// ---------------- weight convert + transpose (13 mats of 64x64) ----------------
// wh[mat][n*64+k] = bf16(W[mat][k*64+n]); Wn(0..5), Wr(6..11), W_out(12)
__global__ __launch_bounds__(256) void wt_kernel(const float* __restrict__ Wn,
                                                 const float* __restrict__ Wr,
                                                 const float* __restrict__ Wout,
                                                 u16* __restrict__ wh) {
    int mat = blockIdx.x;
    const float* src = (mat < 6) ? (Wn + (size_t)mat * 4096)
                     : (mat < 12) ? (Wr + (size_t)(mat - 6) * 4096)
                                  : Wout;
    u16* dstp = wh + (size_t)mat * 4096;
    for (int i = threadIdx.x; i < 4096; i += 256) {
        int k = i >> 6, n = i & 63;
        dstp[n * 64 + k] = (u16)f2bs(src[i]);
    }
}

// ---------------- CSR build: bucketed multisplit ----------------
__global__ __launch_bounds__(256) void bucket_count(const int* __restrict__ d0,
                                                    const int* __restrict__ d1,
                                                    const int* __restrict__ d2,
                                                    int* __restrict__ ghist,
                                                    int NB, int NA, int E, int total, int K) {
    __shared__ int h[1024];
    int tid = threadIdx.x;
    for (int i = tid; i < 1024; i += 256) h[i] = 0;
    __syncthreads();
    for (int i = blockIdx.x * 256 + tid; i < total; i += gridDim.x * 256) {
        int g;
        if (i < E) g = d0[i];
        else if (i < 2 * E) g = NB + d1[i - E];
        else g = NB + NA + d2[i - 2 * E];
        atomicAdd(&h[g >> BSHIFT], 1);
    }
    __syncthreads();
    for (int i = tid; i < K; i += 256)
        if (h[i]) atomicAdd(&ghist[i], h[i]);
}

__global__ __launch_bounds__(256) void bucket_scan(const int* __restrict__ ghist,
                                                   int* __restrict__ bbase,
                                                   int* __restrict__ gcursor,
                                                   int K, int total) {
    __shared__ int ssum[256];
    int tid = threadIdx.x;
    int v[4]; int s = 0;
#pragma unroll
    for (int j = 0; j < 4; j++) {
        int i = tid * 4 + j;
        v[j] = s;
        s += (i < K) ? ghist[i] : 0;
    }
    ssum[tid] = s; __syncthreads();
    for (int off = 1; off < 256; off <<= 1) {
        int t = (tid >= off) ? ssum[tid - off] : 0; __syncthreads();
        ssum[tid] += t; __syncthreads();
    }
    int exc = tid ? ssum[tid - 1] : 0;
#pragma unroll
    for (int j = 0; j < 4; j++) {
        int i = tid * 4 + j;
        if (i < K) { bbase[i] = exc + v[j]; gcursor[i] = exc + v[j]; }
    }
    if (tid == 255) bbase[K] = total;
}

__global__ __launch_bounds__(256) void partition_kernel(
    const int* __restrict__ s0, const int* __restrict__ d0,
    const int* __restrict__ s1, const int* __restrict__ d1,
    const int* __restrict__ s2, const int* __restrict__ d2,
    int* __restrict__ gcursor, int2* __restrict__ pairs,
    int NB, int NA, int E, int total) {
    __shared__ int hist[1024];
    __shared__ int gbase[1024];
    __shared__ int ssum[256];
    __shared__ int2 buf[TILE];
    int tid = threadIdx.x;
    for (int tile = blockIdx.x * TILE; tile < total; tile += gridDim.x * TILE) {
        for (int i = tid; i < 1024; i += 256) hist[i] = 0;
        __syncthreads();
        int cnt = min(TILE, total - tile);
        int myg[32], mysrc[32], myrank[32];
#pragma unroll
        for (int j = 0; j < 32; j++) {
            int idx = tile + j * 256 + tid;
            int g = -1, s = 0;
            if (idx < total) {
                if (idx < E) { s = s0[idx]; g = d0[idx]; }
                else if (idx < 2 * E) { s = s1[idx - E]; g = NB + d1[idx - E]; }
                else { s = s2[idx - 2 * E]; g = NB + NA + d2[idx - 2 * E]; }
            }
            myg[j] = g; mysrc[j] = s;
            if (g >= 0) myrank[j] = atomicAdd(&hist[g >> BSHIFT], 1);
        }
        __syncthreads();
        int l[4]; int base4 = tid * 4; int ts = 0;
#pragma unroll
        for (int j = 0; j < 4; j++) { l[j] = hist[base4 + j]; ts += l[j]; }
        ssum[tid] = ts; __syncthreads();
        for (int off = 1; off < 256; off <<= 1) {
            int t = (tid >= off) ? ssum[tid - off] : 0; __syncthreads();
            ssum[tid] += t; __syncthreads();
        }
        int exc = tid ? ssum[tid - 1] : 0;
#pragma unroll
        for (int j = 0; j < 4; j++) {
            hist[base4 + j] = exc;
            if (l[j]) gbase[base4 + j] = atomicAdd(&gcursor[base4 + j], l[j]);
            exc += l[j];
        }
        __syncthreads();
#pragma unroll
        for (int j = 0; j < 32; j++) {
            if (myg[j] >= 0) {
                int bkt = myg[j] >> BSHIFT;
                buf[hist[bkt] + myrank[j]] = make_int2(mysrc[j], myg[j]);
            }
        }
        __syncthreads();
        for (int i = tid; i < cnt; i += 256) {
            int2 p = buf[i];
            int bkt = p.y >> BSHIFT;
            pairs[gbase[bkt] + (i - hist[bkt])] = p;
        }
        __syncthreads();
    }
}

__global__ __launch_bounds__(256) void bucket_fill(const int2* __restrict__ pairs,
                                                   const int* __restrict__ bbase,
                                                   int* __restrict__ off,
                                                   int* __restrict__ colidx,
                                                   int M, int K) {
    int b = blockIdx.x;
    int gb = b << BSHIFT;
    __shared__ int cnt[1024], cur[1024], ssum[256];
    int tid = threadIdx.x;
    int p0 = bbase[b], p1 = bbase[b + 1];
    for (int i = tid; i < 1024; i += 256) cnt[i] = 0;
    __syncthreads();
    for (int e = p0 + tid; e < p1; e += 256)
        atomicAdd(&cnt[pairs[e].y - gb], 1);
    __syncthreads();
    int l[4], ts = 0;
#pragma unroll
    for (int j = 0; j < 4; j++) { l[j] = cnt[tid * 4 + j]; ts += l[j]; }
    ssum[tid] = ts; __syncthreads();
    for (int o = 1; o < 256; o <<= 1) {
        int t = (tid >= o) ? ssum[tid - o] : 0; __syncthreads();
        ssum[tid] += t; __syncthreads();
    }
    int exc = tid ? ssum[tid - 1] : 0;
#pragma unroll
    for (int j = 0; j < 4; j++) {
        cur[tid * 4 + j] = exc;
        int g = gb + tid * 4 + j;
        if (g < M) off[g] = p0 + exc;
        exc += l[j];
    }
    if (b == K - 1 && tid == 0) off[M] = p1;
    __syncthreads();
    for (int e = p0 + tid; e < p1; e += 256) {
        int2 p = pairs[e];
        int pos = atomicAdd(&cur[p.y - gb], 1);
        colidx[p0 + pos] = p.x;
    }
}

// ---------------- gather-mean: quarter-wave, 32-bit offsets ----------------
// one wave per dst row; 16 lanes per edge, 4 feats/lane (ushort4 = dwordx2);
// quarters process edges e = s0+qh, step 4; cross-quarter reduce via shfl_xor.
__global__ __launch_bounds__(256) void gather_all(const u16* __restrict__ plane,
                                                  const int* __restrict__ colidx,
                                                  const int* __restrict__ off,
                                                  u16* __restrict__ meanB,
                                                  u16* __restrict__ meanA1,
                                                  u16* __restrict__ meanA2,
                                                  int NB, int NA) {
    int wid = (blockIdx.x * 256 + threadIdx.x) >> 6;
    int lane = threadIdx.x & 63;
    int M = NB + 2 * NA;
    if (wid >= M) return;
    const char* tab;
    u16* outp;
    int orow;
    if (wid < NB) { tab = (const char*)plane; outp = meanB; orow = wid; }
    else if (wid < NB + NA) { tab = (const char*)(plane + (size_t)NA * 64); outp = meanA1; orow = wid - NB; }
    else { tab = (const char*)plane; outp = meanA2; orow = wid - NB - NA; }

    int s0 = off[wid], s1 = off[wid + 1];
    int qh = lane >> 4, fl = lane & 15;
    unsigned fo = (unsigned)(fl << 3);          // byte offset within 128B row
    f32x4 a0 = {0.f, 0.f, 0.f, 0.f}, a1 = {0.f, 0.f, 0.f, 0.f};
    int e = s0 + qh;
    for (; e + 4 < s1; e += 8) {
        int c0 = *(const int*)((const char*)colidx + ((unsigned)e << 2));
        int c1 = *(const int*)((const char*)colidx + ((unsigned)(e + 4) << 2));
        uint2 u0 = *(const uint2*)(tab + (((unsigned)c0 << 7) | fo));
        uint2 u1 = *(const uint2*)(tab + (((unsigned)c1 << 7) | fo));
        a0[0] += uif(u0.x << 16); a0[1] += uif(u0.x & 0xFFFF0000u);
        a0[2] += uif(u0.y << 16); a0[3] += uif(u0.y & 0xFFFF0000u);
        a1[0] += uif(u1.x << 16); a1[1] += uif(u1.x & 0xFFFF0000u);
        a1[2] += uif(u1.y << 16); a1[3] += uif(u1.y & 0xFFFF0000u);
    }
    for (; e < s1; e += 4) {
        int c = *(const int*)((const char*)colidx + ((unsigned)e << 2));
        uint2 u = *(const uint2*)(tab + (((unsigned)c << 7) | fo));
        a0[0] += uif(u.x << 16); a0[1] += uif(u.x & 0xFFFF0000u);
        a0[2] += uif(u.y << 16); a0[3] += uif(u.y & 0xFFFF0000u);
    }
#pragma unroll
    for (int i = 0; i < 4; i++) {
        a0[i] += a1[i];
        a0[i] += __shfl_xor(a0[i], 16);
        a0[i] += __shfl_xor(a0[i], 32);
    }
    if (qh == 0) {
        float inv = 1.0f / fmaxf((float)(s1 - s0), 1.0f);
        u16 o[4];
#pragma unroll
        for (int i = 0; i < 4; i++) o[i] = (u16)f2bs(a0[i] * inv);
        *(uint2*)(outp + (size_t)orow * 64 + fl * 4) = *(uint2*)o;
    }
}

// ---------------- fused linear body (bf16 in, MFMA, bf16 or f32 out) ----------------
// Layouts: A[m=lane&15][k=(lane>>4)*8+j], B[k][n=lane&15] (weights pre-transposed),
// C/D row=(lane>>4)*4+reg, col=lane&15.
template <int NM, int NX, int RELU, int OUTF32>
__device__ __forceinline__ void lin_body(
    const u16* __restrict__ m0, const u16* __restrict__ m1,
    const u16* __restrict__ x,
    const u16* __restrict__ Wm0t, const u16* __restrict__ Wm1t,
    const u16* __restrict__ Wx0t, const u16* __restrict__ Wx1t,
    const float* __restrict__ bias0, const float* __restrict__ bias1,
    void* __restrict__ outv, int nrows, int blk) {
    const int lane = threadIdx.x & 63;
    const int wave = threadIdx.x >> 6;
    const int row0 = blk * 64 + wave * 16;
    if (row0 >= nrows) return;
    const int r = lane & 15;
    const int q = lane >> 4;

    short8 wm0f[2][4], wm1f[2][4], wx0f[2][4], wx1f[2][4];
#pragma unroll
    for (int ks = 0; ks < 2; ks++) {
#pragma unroll
        for (int t = 0; t < 4; t++) {
            size_t widx = (size_t)(t * 16 + r) * 64 + ks * 32 + q * 8;
            if (NM >= 1) wm0f[ks][t] = *(const short8*)(Wm0t + widx);
            if (NM >= 2) wm1f[ks][t] = *(const short8*)(Wm1t + widx);
            if (NX >= 1) wx0f[ks][t] = *(const short8*)(Wx0t + widx);
            if (NX >= 2) wx1f[ks][t] = *(const short8*)(Wx1t + widx);
        }
    }

    f32x4 acc[4];
#pragma unroll
    for (int t = 0; t < 4; t++) {
        float bv = bias0[t * 16 + r];
        if (bias1) bv += bias1[t * 16 + r];
        acc[t][0] = bv; acc[t][1] = bv; acc[t][2] = bv; acc[t][3] = bv;
    }

    const int arow = row0 + r;
    const bool avalid = arow < nrows;
    short8 zf;
#pragma unroll
    for (int j = 0; j < 8; j++) zf[j] = 0;

    if (NM >= 1) {
#pragma unroll
        for (int ks = 0; ks < 2; ks++) {
            short8 af = avalid ? *(const short8*)(m0 + (size_t)arow * 64 + ks * 32 + q * 8) : zf;
#pragma unroll
            for (int t = 0; t < 4; t++)
                acc[t] = __builtin_amdgcn_mfma_f32_16x16x32_bf16(af, wm0f[ks][t], acc[t], 0, 0, 0);
        }
    }
    if (NM >= 2) {
#pragma unroll
        for (int ks = 0; ks < 2; ks++) {
            short8 af = avalid ? *(const short8*)(m1 + (size_t)arow * 64 + ks * 32 + q * 8) : zf;
#pragma unroll
            for (int t = 0; t < 4; t++)
                acc[t] = __builtin_amdgcn_mfma_f32_16x16x32_bf16(af, wm1f[ks][t], acc[t], 0, 0, 0);
        }
    }
    if (NX >= 1) {
#pragma unroll
        for (int ks = 0; ks < 2; ks++) {
            short8 xf = avalid ? *(const short8*)(x + (size_t)arow * 64 + ks * 32 + q * 8) : zf;
#pragma unroll
            for (int t = 0; t < 4; t++)
                acc[t] = __builtin_amdgcn_mfma_f32_16x16x32_bf16(xf, wx0f[ks][t], acc[t], 0, 0, 0);
            if (NX >= 2) {
#pragma unroll
                for (int t = 0; t < 4; t++)
                    acc[t] = __builtin_amdgcn_mfma_f32_16x16x32_bf16(xf, wx1f[ks][t], acc[t], 0, 0, 0);
            }
        }
    }

#pragma unroll
    for (int t = 0; t < 4; t++) {
#pragma unroll
        for (int rr = 0; rr < 4; rr++) {
            int row = row0 + q * 4 + rr;
            if (row < nrows) {
                float v = acc[t][rr];
                if (RELU) v = fmaxf(v, 0.0f);
                if (OUTF32) ((float*)outv)[(size_t)row * 64 + t * 16 + r] = v;
                else ((u16*)outv)[(size_t)row * 64 + t * 16 + r] = (u16)f2bs(v);
            }
        }
    }
}

// one layer: B-phase blocks [0,blocksB), A-phase blocks [blocksB,...)
__global__ __launch_bounds__(256) void layer_kernel(
    const u16* __restrict__ plane_in, u16* __restrict__ plane_out,
    const u16* __restrict__ meanB, const u16* __restrict__ meanA1,
    const u16* __restrict__ meanA2, const u16* __restrict__ wh,
    const float* __restrict__ bvec, int l, int NA, int NB, int blocksB) {
    if ((int)blockIdx.x < blocksB) {
        lin_body<1, 1, 0, 0>(meanB, nullptr, plane_in + (size_t)NA * 64,
                             wh + (size_t)(l * 3 + 0) * 4096, nullptr,
                             wh + (size_t)(6 + l * 3 + 0) * 4096, nullptr,
                             bvec + (size_t)(l * 3 + 0) * 64, nullptr,
                             plane_out + (size_t)NA * 64, NB, blockIdx.x);
    } else {
        lin_body<2, 2, 0, 0>(meanA1, meanA2, plane_in,
                             wh + (size_t)(l * 3 + 1) * 4096, wh + (size_t)(l * 3 + 2) * 4096,
                             wh + (size_t)(6 + l * 3 + 1) * 4096, wh + (size_t)(6 + l * 3 + 2) * 4096,
                             bvec + (size_t)(l * 3 + 1) * 64, bvec + (size_t)(l * 3 + 2) * 64,
                             plane_out, NA, blockIdx.x - blocksB);
    }
}

// head over NA+NB contiguous rows
__global__ __launch_bounds__(256) void head_kernel(
    const u16* __restrict__ plane_in, const u16* __restrict__ wh,
    const float* __restrict__ b_out, float* __restrict__ out, int nrows) {
    lin_body<0, 1, 1, 1>(nullptr, nullptr, plane_in,
                         nullptr, nullptr, wh + (size_t)12 * 4096, nullptr,
                         b_out, nullptr, out, nrows, blockIdx.x);
}

// ---------------- launch ----------------
extern "C" void kernel_launch(void* const* d_in, const int* in_sizes, int n_in,
                              void* d_out, int out_size, void* d_ws, size_t ws_size,
                              hipStream_t stream) {
    const float* xA_in = (const float*)d_in[0];
    const float* xB_in = (const float*)d_in[1];
    const float* Wn = (const float*)d_in[2];
    const float* Wr = (const float*)d_in[3];
    const float* b = (const float*)d_in[4];
    const float* W_out = (const float*)d_in[5];
    const float* b_out = (const float*)d_in[6];
    const int* src0 = (const int*)d_in[7];
    const int* dst0 = (const int*)d_in[8];
    const int* src1 = (const int*)d_in[9];
    const int* dst1 = (const int*)d_in[10];
    const int* src2 = (const int*)d_in[11];
    const int* dst2 = (const int*)d_in[12];

    const int NA = in_sizes[0] / 64;
    const int NB = in_sizes[1] / 64;
    const int E = in_sizes[7];
    const int M = NB + NA + NA;
    const int total = 3 * E;
    const int K = (M + (1 << BSHIFT) - 1) >> BSHIFT;

    // ---- workspace: plane0 [xA|xB], plane1 [xA|xB], means, wh, ints ----
    const size_t PL = (size_t)(NA + NB) * 64;
    u16* plane[2];
    plane[0] = (u16*)d_ws;
    plane[1] = plane[0] + PL;
    u16* meanB  = plane[1] + PL;
    u16* meanA1 = meanB + (size_t)NB * 64;
    u16* meanA2 = meanA1 + (size_t)NA * 64;
    u16* wh     = meanA2 + (size_t)NA * 64;
    int* ghist  = (int*)(wh + 13 * 4096);
    int* bbase  = ghist + 1024;
    int* gcursor= bbase + 1025;
    int* off    = gcursor + 1024;
    int* colidx = off + (M + 1);
    int2* pairs = (int2*)meanB;   // aliases means region (dead until gathers run)

    // ---- conversions ----
    cvt_kernel<<<(NA * 16 + 255) / 256, 256, 0, stream>>>(xA_in, plane[0], NA * 16);
    cvt_kernel<<<(NB * 16 + 255) / 256, 256, 0, stream>>>(xB_in, plane[0] + (size_t)NA * 64, NB * 16);
    wt_kernel<<<13, 256, 0, stream>>>(Wn, Wr, W_out, wh);

    // ---- CSR build ----
    hipMemsetAsync(ghist, 0, 1024 * 4, stream);
    bucket_count<<<512, 256, 0, stream>>>(dst0, dst1, dst2, ghist, NB, NA, E, total, K);
    bucket_scan<<<1, 256, 0, stream>>>(ghist, bbase, gcursor, K, total);
    int ntiles = (total + TILE - 1) / TILE;
    partition_kernel<<<ntiles, 256, 0, stream>>>(src0, dst0, src1, dst1, src2, dst2,
                                                 gcursor, pairs, NB, NA, E, total);
    bucket_fill<<<K, 256, 0, stream>>>(pairs, bbase, off, colidx, M, K);

    const int blocksB = (NB + 63) / 64;
    const int blocksA = (NA + 63) / 64;
    int p = 0;
    for (int l = 0; l < 2; l++) {
        gather_all<<<(M + 3) / 4, 256, 0, stream>>>(plane[p], colidx, off,
                                                    meanB, meanA1, meanA2, NB, NA);
        layer_kernel<<<blocksB + blocksA, 256, 0, stream>>>(
            plane[p], plane[1 - p], meanB, meanA1, meanA2, wh, b, l, NA, NB, blocksB);
        p = 1 - p;
    }

    head_kernel<<<(NA + NB + 63) / 64, 256, 0, stream>>>(
        plane[p], wh, b_out, (float*)d_out, NA + NB);
}